// Round 10
// baseline (820.685 us; speedup 1.0000x reference)
//
#include <hip/hip_runtime.h>
#include <stdint.h>

#define DIM   1024
#define HID   2816
#define NEXP  2
#define NTOK  32768
#define RMS_EPS 1e-5f
#define NK1   16            // K-tiles per item, GEMM1 (DIM/64)
#define NK2   44            // K-tiles per item, GEMM2 (HID/64)
#define NNT1  22            // HID/128 column tiles, GEMM1
#define NNT2  4             // DIM/256 column tiles, GEMM2

typedef unsigned short u16;
typedef unsigned int   u32;
typedef __bf16 bf16_t;
typedef bf16_t bf16x8 __attribute__((ext_vector_type(8)));
typedef float  f32x4  __attribute__((ext_vector_type(4)));
typedef float  f32x4v __attribute__((ext_vector_type(4)));

#define BAR() asm volatile("s_barrier" ::: "memory")
#define WAIT6() asm volatile("s_waitcnt vmcnt(6)" ::: "memory")
#define WAIT0() asm volatile("s_waitcnt vmcnt(0)" ::: "memory")
#define MFMA_(a,b,c) __builtin_amdgcn_mfma_f32_16x16x32_bf16(a, b, c, 0, 0, 0)

__device__ __forceinline__ u16 f2bf(float f) {
  u32 u = __float_as_uint(f);
  u += 0x7FFFu + ((u >> 16) & 1u);   // RNE
  return (u16)(u >> 16);
}

__device__ __forceinline__ void gld16(void* lds, const void* g) {
  __builtin_amdgcn_global_load_lds(
      (__attribute__((address_space(1))) void*)g,
      (__attribute__((address_space(3))) void*)lds, 16, 0, 0);
}

// ---------------- mask decoding (layout-robust) ----------------
__device__ __forceinline__ int detect_layout(const u32* mi) {
  const int lane = threadIdx.x & 63;
  bool all01 = true, allf = true;
  for (int j = 0; j < 8; ++j) {
    u32 w = mi[j * 64 + lane];
    all01 &= (w <= 1u);
    allf  &= (w == 0u || w == 0x3F800000u);
  }
  unsigned long long b01 = __ballot(all01);
  unsigned long long bfl = __ballot(allf);
  if (b01 == ~0ull) return 0;
  if (bfl == ~0ull) return 1;
  return 2;
}

__device__ __forceinline__ bool mask_at(const void* m, int layout, int e, int n) {
  if (layout == 0) return ((const u32*)m)[e * NTOK + n] != 0u;
  if (layout == 1) return ((const float*)m)[e * NTOK + n] != 0.f;
  return ((const unsigned char*)m)[e * NTOK + n] != 0;
}

__device__ __forceinline__ int label_of(const void* m, int layout, int n) {
  for (int e = 0; e < NEXP; ++e)
    if (mask_at(m, layout, e, n)) return e;
  return 0;
}

// ---------------- fused prep: block 0 = prefix-scan setup; rest = weight cvt
__global__ __launch_bounds__(1024) void k_prep(
    const void* __restrict__ masks, int* __restrict__ meta, int* __restrict__ idx,
    const float* __restrict__ w1, const float* __restrict__ w3,
    const float* __restrict__ w2, u16* __restrict__ w1b,
    u16* __restrict__ w3b, u16* __restrict__ w2b, int n4)
{
  const int t = threadIdx.x;
  if (blockIdx.x == 0) {
    // deterministic count+scan+fill (1024 threads x 32 tokens)
    const int layout = detect_layout((const u32*)masks);
    const int base_n = t << 5;
    u32 bits = 0; int c0 = 0;
    for (int j = 0; j < 32; ++j) {
      const int l_ = label_of(masks, layout, base_n + j);
      bits |= ((u32)l_) << j;
      c0 += 1 - l_;
    }
    int inc = c0;
#pragma unroll
    for (int d = 1; d < 64; d <<= 1) {
      int v = __shfl_up(inc, d, 64);
      if ((t & 63) >= d) inc += v;
    }
    __shared__ int wsum[16];
    __shared__ int wexc[17];
    const int wv = t >> 6;
    if ((t & 63) == 63) wsum[wv] = inc;
    __syncthreads();
    if (t == 0) {
      int a = 0;
      for (int w = 0; w < 16; ++w) { wexc[w] = a; a += wsum[w]; }
      wexc[16] = a;
    }
    __syncthreads();
    const int cnt0 = wexc[16];
    int p0 = wexc[wv] + inc - c0;
    int p1 = cnt0 + base_n - p0;
    for (int j = 0; j < 32; ++j) {
      const int n = base_n + j;
      if ((bits >> j) & 1u) idx[p1++] = n;
      else                  idx[p0++] = n;
    }
    if (t == 0) { meta[0] = cnt0; meta[1] = NTOK - cnt0; }
    return;
  }
  // weight conversion (grid-stride over 3*n4 float4's), nontemporal loads
  const int stride = (gridDim.x - 1) * blockDim.x;
  for (int i = (blockIdx.x - 1) * blockDim.x + t; i < 3 * n4; i += stride) {
    const f32x4v* src; ushort4* dst; int j;
    if (i < n4)            { src = (const f32x4v*)w1; dst = (ushort4*)w1b; j = i; }
    else if (i < 2 * n4)   { src = (const f32x4v*)w3; dst = (ushort4*)w3b; j = i - n4; }
    else                   { src = (const f32x4v*)w2; dst = (ushort4*)w2b; j = i - 2 * n4; }
    const f32x4v v = __builtin_nontemporal_load(&src[j]);
    ushort4 o;
    o.x = f2bf(v[0]); o.y = f2bf(v[1]); o.z = f2bf(v[2]); o.w = f2bf(v[3]);
    dst[j] = o;
  }
}

// ---------------- x: f32 -> bf16, GATHERED into expert-sorted order --------
__global__ __launch_bounds__(256) void k_cvtx(const float* __restrict__ x,
                                              const int* __restrict__ idx,
                                              u16* __restrict__ xg) {
  const int r = blockIdx.x;
  const int tok = idx[r];
  const f32x4v v = __builtin_nontemporal_load(
      &((const f32x4v*)(x + ((size_t)tok << 10)))[threadIdx.x]);
  ushort4 o;
  o.x = f2bf(v[0]); o.y = f2bf(v[1]); o.z = f2bf(v[2]); o.w = f2bf(v[3]);
  ((ushort4*)(xg + ((size_t)r << 10)))[threadIdx.x] = o;
}

// ============================================================================
// GEMM1 (persistent): h = silu(Xg@W1^T) * (Xg@W3^T), rows pre-gathered.
// 256 blocks, 8 waves, BM=256, BN=128 dual-B, BK=64, 128 KiB LDS (1 blk/CU).
// CONTIGUOUS per-block item range (mT-inner order) -> one B panel per block
// lifetime (staged once, L2-hot); A panels streamed exactly once.
// h stores NONTEMPORAL (write-once stream must not evict A/B from L3).
// ============================================================================

#define ST1A(BUF, HH, P_, KT) {                                        \
    char* _d = (char*)&sA[BUF][(HH) * 8192] + t * 16;                  \
    gld16(_d,        ((HH) ? P_.a2 : P_.a0) + (size_t)(KT) * 64);      \
    gld16(_d + 8192, ((HH) ? P_.a3 : P_.a1) + (size_t)(KT) * 64); }

#define ST1B(BUF, HH, P_, KT) {                                                 \
    gld16((char*)&sB1[BUF][(HH) * 4096] + t * 16,                               \
          ((HH) ? P_.b11 : P_.b10) + (size_t)(KT) * 64);                        \
    gld16((char*)&sB3[BUF][(HH) * 4096] + t * 16,                               \
          ((HH) ? P_.b31 : P_.b30) + (size_t)(KT) * 64); }

#define G1_PH(MQ, NQ, ...) {                                                   \
    if ((NQ) == 0) {                                                           \
      _Pragma("unroll") for (int mi = 0; mi < 4; ++mi) {                       \
        af0[mi] = *(const bf16x8*)&sAc[aBase + (MQ)*8192 + mi*1024 + kb0];     \
        af1[mi] = *(const bf16x8*)&sAc[aBase + (MQ)*8192 + mi*1024 + kb1];     \
      }                                                                        \
    }                                                                          \
    b1f0 = *(const bf16x8*)&sB1c[bBase + (NQ)*4096 + kb0];                     \
    b1f1 = *(const bf16x8*)&sB1c[bBase + (NQ)*4096 + kb1];                     \
    b3f0 = *(const bf16x8*)&sB3c[bBase + (NQ)*4096 + kb0];                     \
    b3f1 = *(const bf16x8*)&sB3c[bBase + (NQ)*4096 + kb1];                     \
    __VA_ARGS__                                                                \
    BAR();                                                                     \
    __builtin_amdgcn_s_setprio(1);                                             \
    _Pragma("unroll") for (int mi = 0; mi < 4; ++mi) {                         \
      acc1[MQ][NQ][mi] = MFMA_(af0[mi], b1f0, acc1[MQ][NQ][mi]);               \
      acc3[MQ][NQ][mi] = MFMA_(af0[mi], b3f0, acc3[MQ][NQ][mi]);               \
      acc1[MQ][NQ][mi] = MFMA_(af1[mi], b1f1, acc1[MQ][NQ][mi]);               \
      acc3[MQ][NQ][mi] = MFMA_(af1[mi], b3f1, acc3[MQ][NQ][mi]);               \
    }                                                                          \
    __builtin_amdgcn_s_setprio(0);                                             \
  }

#define SETUP1(P_, IT) {                                                        \
    int _it = (IT);                                                            \
    int _nt = _it / mcnt;                                                      \
    int _j  = _it - _nt * mcnt;                                                \
    int _m  = c + (_j << 3);                                                   \
    P_.nT   = _nt;                                                             \
    int _e  = _m >= nmt0;                                                      \
    P_.mT   = _e ? _m - nmt0 : _m;                                             \
    P_.cnt  = _e ? cnt1 : cnt0;                                                \
    P_.bas  = _e ? cnt0 : 0;                                                   \
    int _rg;                                                                   \
    _rg = P_.mT*256       + r0; _rg = _rg < P_.cnt ? _rg : P_.cnt-1;           \
    P_.a0 = xg + (size_t)(P_.bas+_rg)*DIM + srcoff;                            \
    _rg = P_.mT*256 +  64 + r0; _rg = _rg < P_.cnt ? _rg : P_.cnt-1;           \
    P_.a1 = xg + (size_t)(P_.bas+_rg)*DIM + srcoff;                            \
    _rg = P_.mT*256 + 128 + r0; _rg = _rg < P_.cnt ? _rg : P_.cnt-1;           \
    P_.a2 = xg + (size_t)(P_.bas+_rg)*DIM + srcoff;                            \
    _rg = P_.mT*256 + 192 + r0; _rg = _rg < P_.cnt ? _rg : P_.cnt-1;           \
    P_.a3 = xg + (size_t)(P_.bas+_rg)*DIM + srcoff;                            \
    size_t _o = ((size_t)_e * HID + (size_t)P_.nT * 128 + r0) * DIM + srcoff;  \
    P_.b10 = w1b + _o; P_.b11 = w1b + _o + (size_t)64 * DIM;                   \
    P_.b30 = w3b + _o; P_.b31 = w3b + _o + (size_t)64 * DIM; }

__global__ __launch_bounds__(512, 1) void k_gemm1(
    const u16* __restrict__ xg, const u16* __restrict__ w1b,
    const u16* __restrict__ w3b, const int* __restrict__ meta,
    u16* __restrict__ h)
{
  const int cnt0 = meta[0], cnt1 = meta[1];
  const int nmt0 = (cnt0 + 255) >> 8;
  const int nmt  = nmt0 + ((cnt1 + 255) >> 8);
  const int c = blockIdx.x & 7, q = blockIdx.x >> 3;
  const int mcnt  = (nmt > c) ? (((nmt - 1 - c) >> 3) + 1) : 0;
  const int items = mcnt * NNT1;
  const int ipb   = (items + 31) >> 5;       // contiguous range per block
  int i = q * ipb;
  const int hi = (i + ipb < items) ? (i + ipb) : items;
  if (i >= hi) return;

  __shared__ __attribute__((aligned(16))) u16 sA [2][256 * 64];
  __shared__ __attribute__((aligned(16))) u16 sB1[2][128 * 64];
  __shared__ __attribute__((aligned(16))) u16 sB3[2][128 * 64];

  const int t = threadIdx.x;
  const int srcoff = ((t & 7) ^ ((t >> 3) & 7)) * 8;   // pre-swizzled src (u16)
  const int r0 = t >> 3;
  const int wid = t >> 6, l = t & 63;
  const int wr = wid >> 2, wc = wid & 3;
  const int l15 = l & 15, lk = l >> 4, l7 = l & 7;
  const int kb0 = ((0 + lk) ^ l7) * 8;
  const int kb1 = ((4 + lk) ^ l7) * 8;
  const int aBase = (wr * 64 + l15) * 64;
  const int bBase = (wc * 16 + l15) * 64;

  struct P { const u16 *a0,*a1,*a2,*a3,*b10,*b11,*b30,*b31; int mT,cnt,bas,nT; };
  P cur, nxt;
  SETUP1(cur, i)
  bool hasN = (i + 1) < hi;
  if (hasN) { SETUP1(nxt, i + 1) } else { nxt = cur; }

  f32x4 acc1[2][2][4] = {};
  f32x4 acc3[2][2][4] = {};
  bf16x8 af0[4], af1[4], b1f0, b1f1, b3f0, b3f1;

  // prologue: step0 full (8 loads) + step1 {A0,A1,Bh0} (6 loads)
  ST1A(0, 0, cur, 0) ST1A(0, 1, cur, 0) ST1B(0, 0, cur, 0) ST1B(0, 1, cur, 0)
  ST1A(1, 0, cur, 1) ST1A(1, 1, cur, 1) ST1B(1, 0, cur, 1)
  WAIT6();
  BAR();

  for (;;) {
#pragma unroll 2
    for (int k = 0; k < NK1 - 2; ++k) {
      const u16* sAc  = &sA [k & 1][0];
      const u16* sB1c = &sB1[k & 1][0];
      const u16* sB3c = &sB3[k & 1][0];
      G1_PH(0, 0, ST1B((k & 1) ^ 1, 1, cur, k + 1))
      BAR();
      G1_PH(0, 1, ST1A(k & 1, 0, cur, k + 2))
      BAR();
      G1_PH(1, 0, )
      BAR();
      G1_PH(1, 1, ST1A(k & 1, 1, cur, k + 2) ST1B(k & 1, 0, cur, k + 2))
      WAIT6();
      BAR();
    }
    {   // k = NK1-2: prefetch slots -> next item's step 0
      const u16* sAc  = &sA [0][0];
      const u16* sB1c = &sB1[0][0];
      const u16* sB3c = &sB3[0][0];
      G1_PH(0, 0, ST1B(1, 1, cur, 15))
      BAR();
      G1_PH(0, 1, if (hasN) ST1A(0, 0, nxt, 0))
      BAR();
      G1_PH(1, 0, )
      BAR();
      G1_PH(1, 1, if (hasN) { ST1A(0, 1, nxt, 0) ST1B(0, 0, nxt, 0) })
      if (hasN) WAIT6(); else WAIT0();
      BAR();
    }
    {   // k = NK1-1: prefetch slots -> next item's steps 0/1
      const u16* sAc  = &sA [1][0];
      const u16* sB1c = &sB1[1][0];
      const u16* sB3c = &sB3[1][0];
      G1_PH(0, 0, if (hasN) ST1B(0, 1, nxt, 0))
      BAR();
      G1_PH(0, 1, if (hasN) ST1A(1, 0, nxt, 1))
      BAR();
      G1_PH(1, 0, )
      BAR();
      G1_PH(1, 1, if (hasN) { ST1A(1, 1, nxt, 1) ST1B(1, 0, nxt, 1) })
      if (hasN) WAIT6();
      BAR();
    }

    // epilogue: h = silu(acc1) * acc3 — nontemporal stores
#pragma unroll
    for (int mq = 0; mq < 2; ++mq)
#pragma unroll
      for (int mi = 0; mi < 4; ++mi)
#pragma unroll
        for (int r = 0; r < 4; ++r) {
          const int lrow = mq * 128 + wr * 64 + mi * 16 + lk * 4 + r;
          const int rg = cur.mT * 256 + lrow;
          if (rg < cur.cnt) {
            u16* hrow = h + (size_t)(cur.bas + rg) * HID + cur.nT * 128 + wc * 16 + l15;
#pragma unroll
            for (int nq = 0; nq < 2; ++nq) {
              const float a = acc1[mq][nq][mi][r];
              const float b = acc3[mq][nq][mi][r];
              __builtin_nontemporal_store(f2bf((a / (1.f + __expf(-a))) * b),
                                          hrow + nq * 64);
            }
          }
        }

    if (!hasN) break;
    cur = nxt;
    i += 1;
    hasN = (i + 1) < hi;
    if (hasN) SETUP1(nxt, i + 1)
#pragma unroll
    for (int a_ = 0; a_ < 2; ++a_)
#pragma unroll
      for (int b_ = 0; b_ < 2; ++b_)
#pragma unroll
        for (int m_ = 0; m_ < 4; ++m_) {
          acc1[a_][b_][m_] = (f32x4){0.f, 0.f, 0.f, 0.f};
          acc3[a_][b_][m_] = (f32x4){0.f, 0.f, 0.f, 0.f};
        }
  }
}

// ============================================================================
// GEMM2 (persistent): O = H @ W2^T, scatter f32 rows.
// CONTIGUOUS ranges + nT-INNER item order: a block's consecutive items share
// one mT -> its h-panel (1.4 MB) is L2-hot; the 4 nT items of an mT run on
// adjacent same-XCD blocks concurrently -> h read ~once per XCD.
// ============================================================================

#define ST2A(BUF, HH, P_, KT) {                                        \
    char* _d = (char*)&sA[BUF][(HH) * 8192] + t * 16;                  \
    gld16(_d,        ((HH) ? P_.a2 : P_.a0) + (size_t)(KT) * 64);      \
    gld16(_d + 8192, ((HH) ? P_.a3 : P_.a1) + (size_t)(KT) * 64); }

#define ST2B(BUF, HH, P_, KT) {                                        \
    char* _d = (char*)&sB[BUF][(HH) * 8192] + t * 16;                  \
    gld16(_d,        ((HH) ? P_.b2 : P_.b0) + (size_t)(KT) * 64);      \
    gld16(_d + 8192, ((HH) ? P_.b3 : P_.b1) + (size_t)(KT) * 64); }

#define G2_PH(MQ, NQ, ...) {                                                   \
    if ((NQ) == 0) {                                                           \
      _Pragma("unroll") for (int mi = 0; mi < 4; ++mi) {                       \
        af0[mi] = *(const bf16x8*)&sAc[aBase + (MQ)*8192 + mi*1024 + kb0];     \
        af1[mi] = *(const bf16x8*)&sAc[aBase + (MQ)*8192 + mi*1024 + kb1];     \
      }                                                                        \
    }                                                                          \
    _Pragma("unroll") for (int ni = 0; ni < 2; ++ni) {                         \
      bf0[ni] = *(const bf16x8*)&sBc[bBase + (NQ)*8192 + ni*1024 + kb0];       \
      bf1[ni] = *(const bf16x8*)&sBc[bBase + (NQ)*8192 + ni*1024 + kb1];       \
    }                                                                          \
    __VA_ARGS__                                                                \
    BAR();                                                                     \
    __builtin_amdgcn_s_setprio(1);                                             \
    _Pragma("unroll") for (int mi = 0; mi < 4; ++mi)                           \
      _Pragma("unroll") for (int ni = 0; ni < 2; ++ni) {                       \
        acc[MQ][NQ][mi][ni] = MFMA_(af0[mi], bf0[ni], acc[MQ][NQ][mi][ni]);    \
        acc[MQ][NQ][mi][ni] = MFMA_(af1[mi], bf1[ni], acc[MQ][NQ][mi][ni]);    \
      }                                                                        \
    __builtin_amdgcn_s_setprio(0);                                             \
  }

#define SETUP2(P_, IT) {                                                        \
    int _it = (IT);                                                            \
    P_.nT   = _it & 3;                                                         \
    int _j  = _it >> 2;                                                        \
    int _m  = c + (_j << 3);                                                   \
    int _e  = _m >= nmt0;                                                      \
    P_.mT   = _e ? _m - nmt0 : _m;                                             \
    P_.cnt  = _e ? cnt1 : cnt0;                                                \
    P_.bas  = _e ? cnt0 : 0;                                                   \
    int _rg;                                                                   \
    _rg = P_.mT*256       + r0; _rg = _rg < P_.cnt ? _rg : P_.cnt-1;           \
    P_.a0 = hbuf + (size_t)(P_.bas+_rg)*HID + srcoff;                          \
    _rg = P_.mT*256 +  64 + r0; _rg = _rg < P_.cnt ? _rg : P_.cnt-1;           \
    P_.a1 = hbuf + (size_t)(P_.bas+_rg)*HID + srcoff;                          \
    _rg = P_.mT*256 + 128 + r0; _rg = _rg < P_.cnt ? _rg : P_.cnt-1;           \
    P_.a2 = hbuf + (size_t)(P_.bas+_rg)*HID + srcoff;                          \
    _rg = P_.mT*256 + 192 + r0; _rg = _rg < P_.cnt ? _rg : P_.cnt-1;           \
    P_.a3 = hbuf + (size_t)(P_.bas+_rg)*HID + srcoff;                          \
    size_t _wb = ((size_t)_e * DIM + (size_t)P_.nT * 256 + r0) * HID + srcoff; \
    P_.b0 = w2b + _wb;                                                         \
    P_.b1 = w2b + _wb + (size_t) 64 * HID;                                     \
    P_.b2 = w2b + _wb + (size_t)128 * HID;                                     \
    P_.b3 = w2b + _wb + (size_t)192 * HID; }

__global__ __launch_bounds__(512, 1) void k_gemm2(
    const u16* __restrict__ hbuf, const u16* __restrict__ w2b,
    const int* __restrict__ meta, const int* __restrict__ idx,
    float* __restrict__ out)
{
  const int cnt0 = meta[0], cnt1 = meta[1];
  const int nmt0 = (cnt0 + 255) >> 8;
  const int nmt  = nmt0 + ((cnt1 + 255) >> 8);
  const int c = blockIdx.x & 7, q = blockIdx.x >> 3;
  const int mcnt  = (nmt > c) ? (((nmt - 1 - c) >> 3) + 1) : 0;
  const int items = mcnt * NNT2;
  const int ipb   = (items + 31) >> 5;
  int i = q * ipb;
  const int hi = (i + ipb < items) ? (i + ipb) : items;
  if (i >= hi) return;

  __shared__ __attribute__((aligned(16))) u16 sA[2][256 * 64];
  __shared__ __attribute__((aligned(16))) u16 sB[2][256 * 64];

  const int t = threadIdx.x;
  const int srcoff = ((t & 7) ^ ((t >> 3) & 7)) * 8;
  const int r0 = t >> 3;
  const int wid = t >> 6, l = t & 63;
  const int wr = wid >> 2, wc = wid & 3;
  const int l15 = l & 15, lk = l >> 4, l7 = l & 7;
  const int kb0 = ((0 + lk) ^ l7) * 8;
  const int kb1 = ((4 + lk) ^ l7) * 8;
  const int aBase = (wr * 64 + l15) * 64;
  const int bBase = (wc * 32 + l15) * 64;

  struct P { const u16 *a0,*a1,*a2,*a3,*b0,*b1,*b2,*b3; int mT,cnt,bas,nT; };
  P cur, nxt;
  SETUP2(cur, i)
  bool hasN = (i + 1) < hi;
  if (hasN) { SETUP2(nxt, i + 1) } else { nxt = cur; }

  f32x4 acc[2][2][4][2] = {};
  bf16x8 af0[4], af1[4], bf0[2], bf1[2];

  ST2A(0, 0, cur, 0) ST2A(0, 1, cur, 0) ST2B(0, 0, cur, 0) ST2B(0, 1, cur, 0)
  ST2A(1, 0, cur, 1) ST2A(1, 1, cur, 1) ST2B(1, 0, cur, 1)
  WAIT6();
  BAR();

  for (;;) {
#pragma unroll 2
    for (int k = 0; k < NK2 - 2; ++k) {
      const u16* sAc = &sA[k & 1][0];
      const u16* sBc = &sB[k & 1][0];
      G2_PH(0, 0, ST2B((k & 1) ^ 1, 1, cur, k + 1))
      BAR();
      G2_PH(0, 1, ST2A(k & 1, 0, cur, k + 2))
      BAR();
      G2_PH(1, 0, )
      BAR();
      G2_PH(1, 1, ST2A(k & 1, 1, cur, k + 2) ST2B(k & 1, 0, cur, k + 2))
      WAIT6();
      BAR();
    }
    {   // k = NK2-2
      const u16* sAc = &sA[0][0];
      const u16* sBc = &sB[0][0];
      G2_PH(0, 0, ST2B(1, 1, cur, NK2 - 1))
      BAR();
      G2_PH(0, 1, if (hasN) ST2A(0, 0, nxt, 0))
      BAR();
      G2_PH(1, 0, )
      BAR();
      G2_PH(1, 1, if (hasN) { ST2A(0, 1, nxt, 0) ST2B(0, 0, nxt, 0) })
      if (hasN) WAIT6(); else WAIT0();
      BAR();
    }
    {   // k = NK2-1
      const u16* sAc = &sA[1][0];
      const u16* sBc = &sB[1][0];
      G2_PH(0, 0, if (hasN) ST2B(0, 1, nxt, 0))
      BAR();
      G2_PH(0, 1, if (hasN) ST2A(1, 0, nxt, 1))
      BAR();
      G2_PH(1, 0, )
      BAR();
      G2_PH(1, 1, if (hasN) { ST2A(1, 1, nxt, 1) ST2B(1, 0, nxt, 1) })
      if (hasN) WAIT6();
      BAR();
    }

#pragma unroll
    for (int mq = 0; mq < 2; ++mq)
#pragma unroll
      for (int mi = 0; mi < 4; ++mi)
#pragma unroll
        for (int r = 0; r < 4; ++r) {
          const int lrow = mq * 128 + wr * 64 + mi * 16 + lk * 4 + r;
          const int rg = cur.mT * 256 + lrow;
          if (rg < cur.cnt) {
            const int tok = idx[cur.bas + rg];
            float* orow = out + (size_t)tok * DIM + cur.nT * 256 + wc * 32 + l15;
#pragma unroll
            for (int nq = 0; nq < 2; ++nq)
#pragma unroll
              for (int ni = 0; ni < 2; ++ni)
                orow[nq * 128 + ni * 16] = acc[mq][nq][mi][ni][r];
          }
        }

    if (!hasN) break;
    cur = nxt;
    i += 1;
    hasN = (i + 1) < hi;
    if (hasN) SETUP2(nxt, i + 1)
#pragma unroll
    for (int a_ = 0; a_ < 2; ++a_)
#pragma unroll
      for (int b_ = 0; b_ < 2; ++b_)
#pragma unroll
        for (int m_ = 0; m_ < 4; ++m_)
#pragma unroll
          for (int n_ = 0; n_ < 2; ++n_)
            acc[a_][b_][m_][n_] = (f32x4){0.f, 0.f, 0.f, 0.f};
  }
}

// ---------------- RMSNorm: 4 rows/block, one row per wave ----------------
__global__ __launch_bounds__(256) void k_rms(
    float* __restrict__ out, const float* __restrict__ nw,
    const int* __restrict__ meta, const int* __restrict__ idx)
{
  const int wv = threadIdx.x >> 6, ln = threadIdx.x & 63;
  const int r = blockIdx.x * 4 + wv;
  const int e = (r >= meta[0]) ? 1 : 0;
  const int tok = idx[r];
  float* row = out + (size_t)tok * DIM;
  const float* g = nw + (size_t)e * DIM;

  float4 v[4];
  float ss = 0.f;
#pragma unroll
  for (int p = 0; p < 4; ++p) {
    v[p] = ((const float4*)row)[p * 64 + ln];
    ss += v[p].x * v[p].x + v[p].y * v[p].y + v[p].z * v[p].z + v[p].w * v[p].w;
  }
#pragma unroll
  for (int off = 32; off; off >>= 1) ss += __shfl_xor(ss, off, 64);
  const float sc = rsqrtf(ss * (1.0f / DIM) + RMS_EPS);
#pragma unroll
  for (int p = 0; p < 4; ++p) {
    const float4 gg = ((const float4*)g)[p * 64 + ln];
    v[p].x *= sc * gg.x; v[p].y *= sc * gg.y;
    v[p].z *= sc * gg.z; v[p].w *= sc * gg.w;
    ((float4*)row)[p * 64 + ln] = v[p];
  }
}

// ---------------- launch ----------------
extern "C" void kernel_launch(void* const* d_in, const int* in_sizes, int n_in,
                              void* d_out, int out_size, void* d_ws, size_t ws_size,
                              hipStream_t stream)
{
  const float* x     = (const float*)d_in[0];
  const void*  masks = d_in[1];
  const float* w1    = (const float*)d_in[2];
  const float* w3    = (const float*)d_in[3];
  const float* w2    = (const float*)d_in[4];
  const float* nw    = (const float*)d_in[5];
  float* out = (float*)d_out;

  char* ws = (char*)d_ws;
  constexpr size_t OFF_IDX = 256;
  constexpr size_t OFF_XB  = OFF_IDX + (size_t)NTOK * 4;
  constexpr size_t OFF_W1B = OFF_XB + (size_t)NTOK * DIM * 2;
  constexpr size_t SZ_W    = (size_t)NEXP * HID * DIM * 2;
  constexpr size_t OFF_W3B = OFF_W1B + SZ_W;
  constexpr size_t OFF_W2B = OFF_W3B + SZ_W;
  constexpr size_t OFF_H   = OFF_W2B + SZ_W;

  int* meta = (int*)ws;
  int* idx  = (int*)(ws + OFF_IDX);
  u16* xg   = (u16*)(ws + OFF_XB);
  u16* w1b  = (u16*)(ws + OFF_W1B);
  u16* w3b  = (u16*)(ws + OFF_W3B);
  u16* w2b  = (u16*)(ws + OFF_W2B);
  u16* h    = (u16*)(ws + OFF_H);

  const int wn4 = NEXP * HID * DIM / 4;
  k_prep<<<1025, 1024, 0, stream>>>(masks, meta, idx, w1, w3, w2,
                                    w1b, w3b, w2b, wn4);
  k_cvtx<<<NTOK, 256, 0, stream>>>(x, idx, xg);

  k_gemm1<<<256, 512, 0, stream>>>(xg, w1b, w3b, meta, h);
  k_gemm2<<<256, 512, 0, stream>>>(h, w2b, meta, idx, out);
  k_rms<<<NTOK / 4, 256, 0, stream>>>(out, nw, meta, idx);
}

// Round 11
// 780.927 us; speedup vs baseline: 1.0509x; 1.0509x over previous
//
#include <hip/hip_runtime.h>
#include <stdint.h>

#define DIM   1024
#define HID   2816
#define NEXP  2
#define NTOK  32768
#define RMS_EPS 1e-5f
#define NK1   16            // K-tiles per item, GEMM1 (DIM/64)
#define NK2   44            // K-tiles per item, GEMM2 (HID/64)
#define NNT1  22            // HID/128 column tiles, GEMM1
#define NNT2  4             // DIM/256 column tiles, GEMM2

typedef unsigned short u16;
typedef unsigned int   u32;
typedef __bf16 bf16_t;
typedef bf16_t bf16x8 __attribute__((ext_vector_type(8)));
typedef float  f32x4  __attribute__((ext_vector_type(4)));
typedef float  f32x4v __attribute__((ext_vector_type(4)));

#define BAR() asm volatile("s_barrier" ::: "memory")
#define WAIT6() asm volatile("s_waitcnt vmcnt(6)" ::: "memory")
#define WAIT0() asm volatile("s_waitcnt vmcnt(0)" ::: "memory")
#define MFMA_(a,b,c) __builtin_amdgcn_mfma_f32_16x16x32_bf16(a, b, c, 0, 0, 0)

__device__ __forceinline__ u16 f2bf(float f) {
  u32 u = __float_as_uint(f);
  u += 0x7FFFu + ((u >> 16) & 1u);   // RNE
  return (u16)(u >> 16);
}

__device__ __forceinline__ void gld16(void* lds, const void* g) {
  __builtin_amdgcn_global_load_lds(
      (__attribute__((address_space(1))) void*)g,
      (__attribute__((address_space(3))) void*)lds, 16, 0, 0);
}

// ---------------- mask decoding (layout-robust) ----------------
__device__ __forceinline__ int detect_layout(const u32* mi) {
  const int lane = threadIdx.x & 63;
  bool all01 = true, allf = true;
  for (int j = 0; j < 8; ++j) {
    u32 w = mi[j * 64 + lane];
    all01 &= (w <= 1u);
    allf  &= (w == 0u || w == 0x3F800000u);
  }
  unsigned long long b01 = __ballot(all01);
  unsigned long long bfl = __ballot(allf);
  if (b01 == ~0ull) return 0;
  if (bfl == ~0ull) return 1;
  return 2;
}

__device__ __forceinline__ bool mask_at(const void* m, int layout, int e, int n) {
  if (layout == 0) return ((const u32*)m)[e * NTOK + n] != 0u;
  if (layout == 1) return ((const float*)m)[e * NTOK + n] != 0.f;
  return ((const unsigned char*)m)[e * NTOK + n] != 0;
}

__device__ __forceinline__ int label_of(const void* m, int layout, int n) {
  for (int e = 0; e < NEXP; ++e)
    if (mask_at(m, layout, e, n)) return e;
  return 0;
}

// ---------------- fused prep: block 0 = prefix-scan setup; rest = weight cvt
__global__ __launch_bounds__(1024) void k_prep(
    const void* __restrict__ masks, int* __restrict__ meta, int* __restrict__ idx,
    const float* __restrict__ w1, const float* __restrict__ w3,
    const float* __restrict__ w2, u16* __restrict__ w1b,
    u16* __restrict__ w3b, u16* __restrict__ w2b, int n4)
{
  const int t = threadIdx.x;
  if (blockIdx.x == 0) {
    const int layout = detect_layout((const u32*)masks);
    const int base_n = t << 5;
    u32 bits = 0; int c0 = 0;
    for (int j = 0; j < 32; ++j) {
      const int l_ = label_of(masks, layout, base_n + j);
      bits |= ((u32)l_) << j;
      c0 += 1 - l_;
    }
    int inc = c0;
#pragma unroll
    for (int d = 1; d < 64; d <<= 1) {
      int v = __shfl_up(inc, d, 64);
      if ((t & 63) >= d) inc += v;
    }
    __shared__ int wsum[16];
    __shared__ int wexc[17];
    const int wv = t >> 6;
    if ((t & 63) == 63) wsum[wv] = inc;
    __syncthreads();
    if (t == 0) {
      int a = 0;
      for (int w = 0; w < 16; ++w) { wexc[w] = a; a += wsum[w]; }
      wexc[16] = a;
    }
    __syncthreads();
    const int cnt0 = wexc[16];
    int p0 = wexc[wv] + inc - c0;
    int p1 = cnt0 + base_n - p0;
    for (int j = 0; j < 32; ++j) {
      const int n = base_n + j;
      if ((bits >> j) & 1u) idx[p1++] = n;
      else                  idx[p0++] = n;
    }
    if (t == 0) { meta[0] = cnt0; meta[1] = NTOK - cnt0; }
    return;
  }
  const int stride = (gridDim.x - 1) * blockDim.x;
  for (int i = (blockIdx.x - 1) * blockDim.x + t; i < 3 * n4; i += stride) {
    const f32x4v* src; ushort4* dst; int j;
    if (i < n4)            { src = (const f32x4v*)w1; dst = (ushort4*)w1b; j = i; }
    else if (i < 2 * n4)   { src = (const f32x4v*)w3; dst = (ushort4*)w3b; j = i - n4; }
    else                   { src = (const f32x4v*)w2; dst = (ushort4*)w2b; j = i - 2 * n4; }
    const f32x4v v = __builtin_nontemporal_load(&src[j]);
    ushort4 o;
    o.x = f2bf(v[0]); o.y = f2bf(v[1]); o.z = f2bf(v[2]); o.w = f2bf(v[3]);
    dst[j] = o;
  }
}

// ---------------- x: f32 -> bf16, GATHERED into expert-sorted order --------
__global__ __launch_bounds__(256) void k_cvtx(const float* __restrict__ x,
                                              const int* __restrict__ idx,
                                              u16* __restrict__ xg) {
  const int r = blockIdx.x;
  const int tok = idx[r];
  const f32x4v v = __builtin_nontemporal_load(
      &((const f32x4v*)(x + ((size_t)tok << 10)))[threadIdx.x]);
  ushort4 o;
  o.x = f2bf(v[0]); o.y = f2bf(v[1]); o.z = f2bf(v[2]); o.w = f2bf(v[3]);
  ((ushort4*)(xg + ((size_t)r << 10)))[threadIdx.x] = o;
}

// ============================================================================
// GEMM1 (persistent): h = silu(Xg@W1^T) * (Xg@W3^T), rows pre-gathered.
// 256 blocks, 8 waves, BM=256, BN=128 dual-B, BK=64, 128 KiB LDS (1 blk/CU).
// STRIDED item assignment (i += 32, mT-inner): block-FIXED mT (A panel read
// once, then L2/L3-hot) sweeping nT. [round-9 best: 433 µs, FETCH 470 MB]
// h stores NONTEMPORAL (write-once stream must not evict A/B from L3).
// ============================================================================

#define ST1A(BUF, HH, P_, KT) {                                        \
    char* _d = (char*)&sA[BUF][(HH) * 8192] + t * 16;                  \
    gld16(_d,        ((HH) ? P_.a2 : P_.a0) + (size_t)(KT) * 64);      \
    gld16(_d + 8192, ((HH) ? P_.a3 : P_.a1) + (size_t)(KT) * 64); }

#define ST1B(BUF, HH, P_, KT) {                                                 \
    gld16((char*)&sB1[BUF][(HH) * 4096] + t * 16,                               \
          ((HH) ? P_.b11 : P_.b10) + (size_t)(KT) * 64);                        \
    gld16((char*)&sB3[BUF][(HH) * 4096] + t * 16,                               \
          ((HH) ? P_.b31 : P_.b30) + (size_t)(KT) * 64); }

#define G1_PH(MQ, NQ, ...) {                                                   \
    if ((NQ) == 0) {                                                           \
      _Pragma("unroll") for (int mi = 0; mi < 4; ++mi) {                       \
        af0[mi] = *(const bf16x8*)&sAc[aBase + (MQ)*8192 + mi*1024 + kb0];     \
        af1[mi] = *(const bf16x8*)&sAc[aBase + (MQ)*8192 + mi*1024 + kb1];     \
      }                                                                        \
    }                                                                          \
    b1f0 = *(const bf16x8*)&sB1c[bBase + (NQ)*4096 + kb0];                     \
    b1f1 = *(const bf16x8*)&sB1c[bBase + (NQ)*4096 + kb1];                     \
    b3f0 = *(const bf16x8*)&sB3c[bBase + (NQ)*4096 + kb0];                     \
    b3f1 = *(const bf16x8*)&sB3c[bBase + (NQ)*4096 + kb1];                     \
    __VA_ARGS__                                                                \
    BAR();                                                                     \
    __builtin_amdgcn_s_setprio(1);                                             \
    _Pragma("unroll") for (int mi = 0; mi < 4; ++mi) {                         \
      acc1[MQ][NQ][mi] = MFMA_(af0[mi], b1f0, acc1[MQ][NQ][mi]);               \
      acc3[MQ][NQ][mi] = MFMA_(af0[mi], b3f0, acc3[MQ][NQ][mi]);               \
      acc1[MQ][NQ][mi] = MFMA_(af1[mi], b1f1, acc1[MQ][NQ][mi]);               \
      acc3[MQ][NQ][mi] = MFMA_(af1[mi], b3f1, acc3[MQ][NQ][mi]);               \
    }                                                                          \
    __builtin_amdgcn_s_setprio(0);                                             \
  }

#define SETUP1(P_, IT) {                                                        \
    int _it = (IT);                                                            \
    int _nt = _it / mcnt;                                                      \
    int _j  = _it - _nt * mcnt;                                                \
    int _m  = c + (_j << 3);                                                   \
    P_.nT   = _nt;                                                             \
    int _e  = _m >= nmt0;                                                      \
    P_.mT   = _e ? _m - nmt0 : _m;                                             \
    P_.cnt  = _e ? cnt1 : cnt0;                                                \
    P_.bas  = _e ? cnt0 : 0;                                                   \
    int _rg;                                                                   \
    _rg = P_.mT*256       + r0; _rg = _rg < P_.cnt ? _rg : P_.cnt-1;           \
    P_.a0 = xg + (size_t)(P_.bas+_rg)*DIM + srcoff;                            \
    _rg = P_.mT*256 +  64 + r0; _rg = _rg < P_.cnt ? _rg : P_.cnt-1;           \
    P_.a1 = xg + (size_t)(P_.bas+_rg)*DIM + srcoff;                            \
    _rg = P_.mT*256 + 128 + r0; _rg = _rg < P_.cnt ? _rg : P_.cnt-1;           \
    P_.a2 = xg + (size_t)(P_.bas+_rg)*DIM + srcoff;                            \
    _rg = P_.mT*256 + 192 + r0; _rg = _rg < P_.cnt ? _rg : P_.cnt-1;           \
    P_.a3 = xg + (size_t)(P_.bas+_rg)*DIM + srcoff;                            \
    size_t _o = ((size_t)_e * HID + (size_t)P_.nT * 128 + r0) * DIM + srcoff;  \
    P_.b10 = w1b + _o; P_.b11 = w1b + _o + (size_t)64 * DIM;                   \
    P_.b30 = w3b + _o; P_.b31 = w3b + _o + (size_t)64 * DIM; }

__global__ __launch_bounds__(512, 1) void k_gemm1(
    const u16* __restrict__ xg, const u16* __restrict__ w1b,
    const u16* __restrict__ w3b, const int* __restrict__ meta,
    u16* __restrict__ h)
{
  const int cnt0 = meta[0], cnt1 = meta[1];
  const int nmt0 = (cnt0 + 255) >> 8;
  const int nmt  = nmt0 + ((cnt1 + 255) >> 8);
  const int c = blockIdx.x & 7, q = blockIdx.x >> 3;
  const int mcnt  = (nmt > c) ? (((nmt - 1 - c) >> 3) + 1) : 0;
  const int items = mcnt * NNT1;
  int i = q;
  if (i >= items) return;

  __shared__ __attribute__((aligned(16))) u16 sA [2][256 * 64];
  __shared__ __attribute__((aligned(16))) u16 sB1[2][128 * 64];
  __shared__ __attribute__((aligned(16))) u16 sB3[2][128 * 64];

  const int t = threadIdx.x;
  const int srcoff = ((t & 7) ^ ((t >> 3) & 7)) * 8;   // pre-swizzled src (u16)
  const int r0 = t >> 3;
  const int wid = t >> 6, l = t & 63;
  const int wr = wid >> 2, wc = wid & 3;
  const int l15 = l & 15, lk = l >> 4, l7 = l & 7;
  const int kb0 = ((0 + lk) ^ l7) * 8;
  const int kb1 = ((4 + lk) ^ l7) * 8;
  const int aBase = (wr * 64 + l15) * 64;
  const int bBase = (wc * 16 + l15) * 64;

  struct P { const u16 *a0,*a1,*a2,*a3,*b10,*b11,*b30,*b31; int mT,cnt,bas,nT; };
  P cur, nxt;
  SETUP1(cur, i)
  bool hasN = (i + 32) < items;
  if (hasN) { SETUP1(nxt, i + 32) } else { nxt = cur; }

  f32x4 acc1[2][2][4] = {};
  f32x4 acc3[2][2][4] = {};
  bf16x8 af0[4], af1[4], b1f0, b1f1, b3f0, b3f1;

  // prologue: step0 full (8 loads) + step1 {A0,A1,Bh0} (6 loads)
  ST1A(0, 0, cur, 0) ST1A(0, 1, cur, 0) ST1B(0, 0, cur, 0) ST1B(0, 1, cur, 0)
  ST1A(1, 0, cur, 1) ST1A(1, 1, cur, 1) ST1B(1, 0, cur, 1)
  WAIT6();
  BAR();

  for (;;) {
#pragma unroll 2
    for (int k = 0; k < NK1 - 2; ++k) {
      const u16* sAc  = &sA [k & 1][0];
      const u16* sB1c = &sB1[k & 1][0];
      const u16* sB3c = &sB3[k & 1][0];
      G1_PH(0, 0, ST1B((k & 1) ^ 1, 1, cur, k + 1))
      BAR();
      G1_PH(0, 1, ST1A(k & 1, 0, cur, k + 2))
      BAR();
      G1_PH(1, 0, )
      BAR();
      G1_PH(1, 1, ST1A(k & 1, 1, cur, k + 2) ST1B(k & 1, 0, cur, k + 2))
      WAIT6();
      BAR();
    }
    {   // k = NK1-2: prefetch slots -> next item's step 0
      const u16* sAc  = &sA [0][0];
      const u16* sB1c = &sB1[0][0];
      const u16* sB3c = &sB3[0][0];
      G1_PH(0, 0, ST1B(1, 1, cur, 15))
      BAR();
      G1_PH(0, 1, if (hasN) ST1A(0, 0, nxt, 0))
      BAR();
      G1_PH(1, 0, )
      BAR();
      G1_PH(1, 1, if (hasN) { ST1A(0, 1, nxt, 0) ST1B(0, 0, nxt, 0) })
      if (hasN) WAIT6(); else WAIT0();
      BAR();
    }
    {   // k = NK1-1: prefetch slots -> next item's steps 0/1
      const u16* sAc  = &sA [1][0];
      const u16* sB1c = &sB1[1][0];
      const u16* sB3c = &sB3[1][0];
      G1_PH(0, 0, if (hasN) ST1B(0, 1, nxt, 0))
      BAR();
      G1_PH(0, 1, if (hasN) ST1A(1, 0, nxt, 1))
      BAR();
      G1_PH(1, 0, )
      BAR();
      G1_PH(1, 1, if (hasN) { ST1A(1, 1, nxt, 1) ST1B(1, 0, nxt, 1) })
      if (hasN) WAIT6();
      BAR();
    }

    // epilogue: h = silu(acc1) * acc3 — nontemporal stores
#pragma unroll
    for (int mq = 0; mq < 2; ++mq)
#pragma unroll
      for (int mi = 0; mi < 4; ++mi)
#pragma unroll
        for (int r = 0; r < 4; ++r) {
          const int lrow = mq * 128 + wr * 64 + mi * 16 + lk * 4 + r;
          const int rg = cur.mT * 256 + lrow;
          if (rg < cur.cnt) {
            u16* hrow = h + (size_t)(cur.bas + rg) * HID + cur.nT * 128 + wc * 16 + l15;
#pragma unroll
            for (int nq = 0; nq < 2; ++nq) {
              const float a = acc1[mq][nq][mi][r];
              const float b = acc3[mq][nq][mi][r];
              __builtin_nontemporal_store(f2bf((a / (1.f + __expf(-a))) * b),
                                          hrow + nq * 64);
            }
          }
        }

    if (!hasN) break;
    cur = nxt;
    i += 32;
    hasN = (i + 32) < items;
    if (hasN) SETUP1(nxt, i + 32)
#pragma unroll
    for (int a_ = 0; a_ < 2; ++a_)
#pragma unroll
      for (int b_ = 0; b_ < 2; ++b_)
#pragma unroll
        for (int m_ = 0; m_ < 4; ++m_) {
          acc1[a_][b_][m_] = (f32x4){0.f, 0.f, 0.f, 0.f};
          acc3[a_][b_][m_] = (f32x4){0.f, 0.f, 0.f, 0.f};
        }
  }
}

// ============================================================================
// GEMM2 (persistent): O = H @ W2^T, scatter f32 rows. Same structure,
// strided assignment (block-fixed mT -> h panel read once, L2/L3-hot).
// ============================================================================

#define ST2A(BUF, HH, P_, KT) {                                        \
    char* _d = (char*)&sA[BUF][(HH) * 8192] + t * 16;                  \
    gld16(_d,        ((HH) ? P_.a2 : P_.a0) + (size_t)(KT) * 64);      \
    gld16(_d + 8192, ((HH) ? P_.a3 : P_.a1) + (size_t)(KT) * 64); }

#define ST2B(BUF, HH, P_, KT) {                                        \
    char* _d = (char*)&sB[BUF][(HH) * 8192] + t * 16;                  \
    gld16(_d,        ((HH) ? P_.b2 : P_.b0) + (size_t)(KT) * 64);      \
    gld16(_d + 8192, ((HH) ? P_.b3 : P_.b1) + (size_t)(KT) * 64); }

#define G2_PH(MQ, NQ, ...) {                                                   \
    if ((NQ) == 0) {                                                           \
      _Pragma("unroll") for (int mi = 0; mi < 4; ++mi) {                       \
        af0[mi] = *(const bf16x8*)&sAc[aBase + (MQ)*8192 + mi*1024 + kb0];     \
        af1[mi] = *(const bf16x8*)&sAc[aBase + (MQ)*8192 + mi*1024 + kb1];     \
      }                                                                        \
    }                                                                          \
    _Pragma("unroll") for (int ni = 0; ni < 2; ++ni) {                         \
      bf0[ni] = *(const bf16x8*)&sBc[bBase + (NQ)*8192 + ni*1024 + kb0];       \
      bf1[ni] = *(const bf16x8*)&sBc[bBase + (NQ)*8192 + ni*1024 + kb1];       \
    }                                                                          \
    __VA_ARGS__                                                                \
    BAR();                                                                     \
    __builtin_amdgcn_s_setprio(1);                                             \
    _Pragma("unroll") for (int mi = 0; mi < 4; ++mi)                           \
      _Pragma("unroll") for (int ni = 0; ni < 2; ++ni) {                       \
        acc[MQ][NQ][mi][ni] = MFMA_(af0[mi], bf0[ni], acc[MQ][NQ][mi][ni]);    \
        acc[MQ][NQ][mi][ni] = MFMA_(af1[mi], bf1[ni], acc[MQ][NQ][mi][ni]);    \
      }                                                                        \
    __builtin_amdgcn_s_setprio(0);                                             \
  }

#define SETUP2(P_, IT) {                                                        \
    int _it = (IT);                                                            \
    int _nt = _it / mcnt;                                                      \
    int _j  = _it - _nt * mcnt;                                                \
    int _m  = c + (_j << 3);                                                   \
    P_.nT   = _nt;                                                             \
    int _e  = _m >= nmt0;                                                      \
    P_.mT   = _e ? _m - nmt0 : _m;                                             \
    P_.cnt  = _e ? cnt1 : cnt0;                                                \
    P_.bas  = _e ? cnt0 : 0;                                                   \
    int _rg;                                                                   \
    _rg = P_.mT*256       + r0; _rg = _rg < P_.cnt ? _rg : P_.cnt-1;           \
    P_.a0 = hbuf + (size_t)(P_.bas+_rg)*HID + srcoff;                          \
    _rg = P_.mT*256 +  64 + r0; _rg = _rg < P_.cnt ? _rg : P_.cnt-1;           \
    P_.a1 = hbuf + (size_t)(P_.bas+_rg)*HID + srcoff;                          \
    _rg = P_.mT*256 + 128 + r0; _rg = _rg < P_.cnt ? _rg : P_.cnt-1;           \
    P_.a2 = hbuf + (size_t)(P_.bas+_rg)*HID + srcoff;                          \
    _rg = P_.mT*256 + 192 + r0; _rg = _rg < P_.cnt ? _rg : P_.cnt-1;           \
    P_.a3 = hbuf + (size_t)(P_.bas+_rg)*HID + srcoff;                          \
    size_t _wb = ((size_t)_e * DIM + (size_t)P_.nT * 256 + r0) * HID + srcoff; \
    P_.b0 = w2b + _wb;                                                         \
    P_.b1 = w2b + _wb + (size_t) 64 * HID;                                     \
    P_.b2 = w2b + _wb + (size_t)128 * HID;                                     \
    P_.b3 = w2b + _wb + (size_t)192 * HID; }

__global__ __launch_bounds__(512, 1) void k_gemm2(
    const u16* __restrict__ hbuf, const u16* __restrict__ w2b,
    const int* __restrict__ meta, const int* __restrict__ idx,
    float* __restrict__ out)
{
  const int cnt0 = meta[0], cnt1 = meta[1];
  const int nmt0 = (cnt0 + 255) >> 8;
  const int nmt  = nmt0 + ((cnt1 + 255) >> 8);
  const int c = blockIdx.x & 7, q = blockIdx.x >> 3;
  const int mcnt  = (nmt > c) ? (((nmt - 1 - c) >> 3) + 1) : 0;
  const int items = mcnt * NNT2;
  int i = q;
  if (i >= items) return;

  __shared__ __attribute__((aligned(16))) u16 sA[2][256 * 64];
  __shared__ __attribute__((aligned(16))) u16 sB[2][256 * 64];

  const int t = threadIdx.x;
  const int srcoff = ((t & 7) ^ ((t >> 3) & 7)) * 8;
  const int r0 = t >> 3;
  const int wid = t >> 6, l = t & 63;
  const int wr = wid >> 2, wc = wid & 3;
  const int l15 = l & 15, lk = l >> 4, l7 = l & 7;
  const int kb0 = ((0 + lk) ^ l7) * 8;
  const int kb1 = ((4 + lk) ^ l7) * 8;
  const int aBase = (wr * 64 + l15) * 64;
  const int bBase = (wc * 32 + l15) * 64;

  struct P { const u16 *a0,*a1,*a2,*a3,*b0,*b1,*b2,*b3; int mT,cnt,bas,nT; };
  P cur, nxt;
  SETUP2(cur, i)
  bool hasN = (i + 32) < items;
  if (hasN) { SETUP2(nxt, i + 32) } else { nxt = cur; }

  f32x4 acc[2][2][4][2] = {};
  bf16x8 af0[4], af1[4], bf0[2], bf1[2];

  ST2A(0, 0, cur, 0) ST2A(0, 1, cur, 0) ST2B(0, 0, cur, 0) ST2B(0, 1, cur, 0)
  ST2A(1, 0, cur, 1) ST2A(1, 1, cur, 1) ST2B(1, 0, cur, 1)
  WAIT6();
  BAR();

  for (;;) {
#pragma unroll 2
    for (int k = 0; k < NK2 - 2; ++k) {
      const u16* sAc = &sA[k & 1][0];
      const u16* sBc = &sB[k & 1][0];
      G2_PH(0, 0, ST2B((k & 1) ^ 1, 1, cur, k + 1))
      BAR();
      G2_PH(0, 1, ST2A(k & 1, 0, cur, k + 2))
      BAR();
      G2_PH(1, 0, )
      BAR();
      G2_PH(1, 1, ST2A(k & 1, 1, cur, k + 2) ST2B(k & 1, 0, cur, k + 2))
      WAIT6();
      BAR();
    }
    {   // k = NK2-2
      const u16* sAc = &sA[0][0];
      const u16* sBc = &sB[0][0];
      G2_PH(0, 0, ST2B(1, 1, cur, NK2 - 1))
      BAR();
      G2_PH(0, 1, if (hasN) ST2A(0, 0, nxt, 0))
      BAR();
      G2_PH(1, 0, )
      BAR();
      G2_PH(1, 1, if (hasN) { ST2A(0, 1, nxt, 0) ST2B(0, 0, nxt, 0) })
      if (hasN) WAIT6(); else WAIT0();
      BAR();
    }
    {   // k = NK2-1
      const u16* sAc = &sA[1][0];
      const u16* sBc = &sB[1][0];
      G2_PH(0, 0, if (hasN) ST2B(0, 1, nxt, 0))
      BAR();
      G2_PH(0, 1, if (hasN) ST2A(1, 0, nxt, 1))
      BAR();
      G2_PH(1, 0, )
      BAR();
      G2_PH(1, 1, if (hasN) { ST2A(1, 1, nxt, 1) ST2B(1, 0, nxt, 1) })
      if (hasN) WAIT6();
      BAR();
    }

#pragma unroll
    for (int mq = 0; mq < 2; ++mq)
#pragma unroll
      for (int mi = 0; mi < 4; ++mi)
#pragma unroll
        for (int r = 0; r < 4; ++r) {
          const int lrow = mq * 128 + wr * 64 + mi * 16 + lk * 4 + r;
          const int rg = cur.mT * 256 + lrow;
          if (rg < cur.cnt) {
            const int tok = idx[cur.bas + rg];
            float* orow = out + (size_t)tok * DIM + cur.nT * 256 + wc * 32 + l15;
#pragma unroll
            for (int nq = 0; nq < 2; ++nq)
#pragma unroll
              for (int ni = 0; ni < 2; ++ni)
                orow[nq * 128 + ni * 16] = acc[mq][nq][mi][ni][r];
          }
        }

    if (!hasN) break;
    cur = nxt;
    i += 32;
    hasN = (i + 32) < items;
    if (hasN) SETUP2(nxt, i + 32)
#pragma unroll
    for (int a_ = 0; a_ < 2; ++a_)
#pragma unroll
      for (int b_ = 0; b_ < 2; ++b_)
#pragma unroll
        for (int m_ = 0; m_ < 4; ++m_)
#pragma unroll
          for (int n_ = 0; n_ < 2; ++n_)
            acc[a_][b_][m_][n_] = (f32x4){0.f, 0.f, 0.f, 0.f};
  }
}

// ---------------- RMSNorm: 4 rows/block, one row per wave ----------------
__global__ __launch_bounds__(256) void k_rms(
    float* __restrict__ out, const float* __restrict__ nw,
    const int* __restrict__ meta, const int* __restrict__ idx)
{
  const int wv = threadIdx.x >> 6, ln = threadIdx.x & 63;
  const int r = blockIdx.x * 4 + wv;
  const int e = (r >= meta[0]) ? 1 : 0;
  const int tok = idx[r];
  float* row = out + (size_t)tok * DIM;
  const float* g = nw + (size_t)e * DIM;

  float4 v[4];
  float ss = 0.f;
#pragma unroll
  for (int p = 0; p < 4; ++p) {
    v[p] = ((const float4*)row)[p * 64 + ln];
    ss += v[p].x * v[p].x + v[p].y * v[p].y + v[p].z * v[p].z + v[p].w * v[p].w;
  }
#pragma unroll
  for (int off = 32; off; off >>= 1) ss += __shfl_xor(ss, off, 64);
  const float sc = rsqrtf(ss * (1.0f / DIM) + RMS_EPS);
#pragma unroll
  for (int p = 0; p < 4; ++p) {
    const float4 gg = ((const float4*)g)[p * 64 + ln];
    v[p].x *= sc * gg.x; v[p].y *= sc * gg.y;
    v[p].z *= sc * gg.z; v[p].w *= sc * gg.w;
    ((float4*)row)[p * 64 + ln] = v[p];
  }
}

// ---------------- launch ----------------
extern "C" void kernel_launch(void* const* d_in, const int* in_sizes, int n_in,
                              void* d_out, int out_size, void* d_ws, size_t ws_size,
                              hipStream_t stream)
{
  const float* x     = (const float*)d_in[0];
  const void*  masks = d_in[1];
  const float* w1    = (const float*)d_in[2];
  const float* w3    = (const float*)d_in[3];
  const float* w2    = (const float*)d_in[4];
  const float* nw    = (const float*)d_in[5];
  float* out = (float*)d_out;

  char* ws = (char*)d_ws;
  constexpr size_t OFF_IDX = 256;
  constexpr size_t OFF_XB  = OFF_IDX + (size_t)NTOK * 4;
  constexpr size_t OFF_W1B = OFF_XB + (size_t)NTOK * DIM * 2;
  constexpr size_t SZ_W    = (size_t)NEXP * HID * DIM * 2;
  constexpr size_t OFF_W3B = OFF_W1B + SZ_W;
  constexpr size_t OFF_W2B = OFF_W3B + SZ_W;
  constexpr size_t OFF_H   = OFF_W2B + SZ_W;

  int* meta = (int*)ws;
  int* idx  = (int*)(ws + OFF_IDX);
  u16* xg   = (u16*)(ws + OFF_XB);
  u16* w1b  = (u16*)(ws + OFF_W1B);
  u16* w3b  = (u16*)(ws + OFF_W3B);
  u16* w2b  = (u16*)(ws + OFF_W2B);
  u16* h    = (u16*)(ws + OFF_H);

  const int wn4 = NEXP * HID * DIM / 4;
  k_prep<<<1025, 1024, 0, stream>>>(masks, meta, idx, w1, w3, w2,
                                    w1b, w3b, w2b, wn4);
  k_cvtx<<<NTOK, 256, 0, stream>>>(x, idx, xg);

  k_gemm1<<<256, 512, 0, stream>>>(xg, w1b, w3b, meta, h);
  k_gemm2<<<256, 512, 0, stream>>>(h, w2b, meta, idx, out);
  k_rms<<<NTOK / 4, 256, 0, stream>>>(out, nw, meta, idx);
}